// Round 1
// baseline (518.559 us; speedup 1.0000x reference)
//
#include <hip/hip_runtime.h>
#include <stdint.h>

// Problem constants
#define B_    8
#define CIN   1024
#define H_    64
#define W_    48
#define OC    512
#define HW    3072          // H*W
#define NPOS  24576         // B*H*W
#define K9    9216          // 9*CIN
#define HP    66            // H+2
#define WP    50            // W+2

typedef __attribute__((ext_vector_type(8))) __bf16 bf16x8;
typedef __attribute__((ext_vector_type(4))) float  float4_t;
typedef __attribute__((ext_vector_type(4))) unsigned short ushort4_t;

__device__ __forceinline__ unsigned short f2bf(float x) {
  union { float f; unsigned u; } v; v.f = x;
  unsigned r = v.u + 0x7FFFu + ((v.u >> 16) & 1u);
  return (unsigned short)(r >> 16);
}

__device__ __forceinline__ void async16(const void* g, void* l) {
  __builtin_amdgcn_global_load_lds(
      (const __attribute__((address_space(1))) unsigned int*)g,
      (__attribute__((address_space(3))) unsigned int*)l, 16, 0, 0);
}

__device__ __forceinline__ float wave_sum(float v) {
  for (int o = 32; o > 0; o >>= 1) v += __shfl_down(v, o, 64);
  return v;
}

// ---------------- prep: pad+transpose base_feat NCHW fp32 -> NHWC bf16 (padded) ----------
// grid (8 c-chunks, 64 h, 8 b), 256 threads
__global__ void prep_x(const float* __restrict__ x, unsigned short* __restrict__ xt) {
  int cx = blockIdx.x, h = blockIdx.y, b = blockIdx.z;
  __shared__ float tile[128 * 49];
  int t = threadIdx.x;
  const float* src = x + ((long)(b * CIN + cx * 128) * H_ + h) * W_;
  for (int it = 0; it < 24; ++it) {
    int e = it * 256 + t;
    int cl = e / 48, w = e % 48;
    tile[cl * 49 + w] = src[(long)cl * HW + w];
  }
  __syncthreads();
  unsigned short* dst = xt + ((long)(b * HP + h + 1) * WP + 1) * CIN + cx * 128;
  for (int it = 0; it < 24; ++it) {
    int e = it * 256 + t;
    int w = e >> 7, cl = e & 127;
    dst[(long)w * CIN + cl] = f2bf(tile[cl * 49 + w]);
  }
}

// ---------------- prep: W_conv [512,1024,3,3] fp32 -> Wa [512, 9216] bf16, k=(off*1024+c)
__global__ void prep_w(const float* __restrict__ Wc, unsigned short* __restrict__ Wa) {
  long i = (long)blockIdx.x * 256 + threadIdx.x;   // < 4718592
  int o = (int)(i / K9); int rem = (int)(i % K9);
  int off = rem / CIN; int c = rem % CIN;
  Wa[i] = f2bf(Wc[(long)o * K9 + c * 9 + off]);
}

// ---------------- prep: head weights -> Wh [64,512] bf16 (rows 54..63 zero) -------------
__global__ void prep_wh(const float* __restrict__ Wcls, const float* __restrict__ Wbb,
                        unsigned short* __restrict__ Wh) {
  int i = blockIdx.x * 256 + threadIdx.x;   // < 32768
  int m = i >> 9, c = i & 511;
  float v = 0.f;
  if (m < 18) v = Wcls[m * 512 + c];
  else if (m < 54) v = Wbb[(m - 18) * 512 + c];
  Wh[i] = f2bf(v);
}

// ---------------- main conv GEMM: conv1[n][m] = relu(sum_k Wa[m][k]*im2col[n][k] + b[m]) -
// M=512, N=24576, K=9216. 128x128 tile, BK=32. grid (192, 4), 256 threads.
#define BK 32
__global__ __launch_bounds__(256, 2)
void conv_gemm(const unsigned short* __restrict__ Wa, const unsigned short* __restrict__ xt,
               const float* __restrict__ bias, unsigned short* __restrict__ conv1) {
  __shared__ unsigned short As[128 * BK];
  __shared__ unsigned short Bs[128 * BK];
  int t = threadIdx.x;
  int lane = t & 63, wv = t >> 6;
  int m0 = blockIdx.y * 128;
  int n0 = blockIdx.x * 128;
  int srow = wv * 16 + (lane >> 2);
  int skof = (lane & 3) * 8;
  long bpos[2];
  for (int q = 0; q < 2; ++q) {
    int n = n0 + q * 64 + srow;
    int b = n / HW; int rem = n % HW; int h = rem / W_; int w = rem % W_;
    bpos[q] = ((long)(b * HP + h) * WP + w) * CIN;
  }
  float4_t acc[4][4] = {};
  int wm = wv >> 1, wn = wv & 1;
  int quad = lane >> 4, col = lane & 15;
  const int KT = K9 / BK;   // 288
  for (int kt = 0; kt < KT; ++kt) {
    int k0 = kt * BK;
    int off = kt >> 5;                      // k0 / 1024
    int c0 = (kt & 31) * BK + skof;
    int dy = off / 3, dx = off % 3;
    long boff = (long)(dy * WP + dx) * CIN + c0;
    __syncthreads();
    for (int q = 0; q < 2; ++q)
      async16(Wa + (long)(m0 + q * 64 + srow) * K9 + k0 + skof, &As[q * 2048 + wv * 512]);
    for (int q = 0; q < 2; ++q)
      async16(xt + bpos[q] + boff, &Bs[q * 2048 + wv * 512]);
    __syncthreads();
    bf16x8 af[4], bfr[4];
    for (int i = 0; i < 4; ++i)
      af[i] = *(const bf16x8*)&As[(wm * 64 + i * 16 + col) * BK + quad * 8];
    for (int j = 0; j < 4; ++j)
      bfr[j] = *(const bf16x8*)&Bs[(wn * 64 + j * 16 + col) * BK + quad * 8];
    for (int i = 0; i < 4; ++i)
      for (int j = 0; j < 4; ++j)
        acc[i][j] = __builtin_amdgcn_mfma_f32_16x16x32_bf16(af[i], bfr[j], acc[i][j], 0, 0, 0);
  }
  // epilogue: bias + relu, store bf16 conv1[n*512 + m], 8B packed along m
  for (int i = 0; i < 4; ++i) {
    int mb = m0 + wm * 64 + i * 16 + quad * 4;
    float b0 = bias[mb + 0], b1 = bias[mb + 1], b2 = bias[mb + 2], b3 = bias[mb + 3];
    for (int j = 0; j < 4; ++j) {
      int n = n0 + wn * 64 + j * 16 + col;
      ushort4_t pk;
      pk.x = f2bf(fmaxf(acc[i][j].x + b0, 0.f));
      pk.y = f2bf(fmaxf(acc[i][j].y + b1, 0.f));
      pk.z = f2bf(fmaxf(acc[i][j].z + b2, 0.f));
      pk.w = f2bf(fmaxf(acc[i][j].w + b3, 0.f));
      *(ushort4_t*)&conv1[(long)n * 512 + mb] = pk;
    }
  }
}

// ---------------- head GEMM: [64 x 512] @ conv1^T -> cls_score (ws) + bbox_pred (d_out) --
// M=64 (54 used), N=24576, K=512. Tile 64x128. grid 192, 256 threads.
__global__ __launch_bounds__(256, 2)
void head_gemm(const unsigned short* __restrict__ Wh, const unsigned short* __restrict__ conv1,
               const float* __restrict__ b_cls, const float* __restrict__ b_bbox,
               float* __restrict__ cls_ws, float* __restrict__ out_bbox) {
  __shared__ unsigned short As[64 * 32];
  __shared__ unsigned short Bs[128 * 32];
  int t = threadIdx.x;
  int lane = t & 63, wv = t >> 6;
  int n0 = blockIdx.x * 128;
  int srow = wv * 16 + (lane >> 2);
  int skof = (lane & 3) * 8;
  int quad = lane >> 4, col = lane & 15;
  float4_t acc[4][2] = {};
  for (int kt = 0; kt < 16; ++kt) {
    int k0 = kt * 32;
    __syncthreads();
    async16(Wh + (long)srow * 512 + k0 + skof, &As[wv * 512]);
    for (int q = 0; q < 2; ++q)
      async16(conv1 + (long)(n0 + q * 64 + srow) * 512 + k0 + skof, &Bs[q * 2048 + wv * 512]);
    __syncthreads();
    bf16x8 af[4], bfr[2];
    for (int i = 0; i < 4; ++i)
      af[i] = *(const bf16x8*)&As[(i * 16 + col) * 32 + quad * 8];
    for (int j = 0; j < 2; ++j)
      bfr[j] = *(const bf16x8*)&Bs[(wv * 32 + j * 16 + col) * 32 + quad * 8];
    for (int i = 0; i < 4; ++i)
      for (int j = 0; j < 2; ++j)
        acc[i][j] = __builtin_amdgcn_mfma_f32_16x16x32_bf16(af[i], bfr[j], acc[i][j], 0, 0, 0);
  }
  for (int j = 0; j < 2; ++j) {
    int n = n0 + wv * 32 + j * 16 + col;
    int b = n / HW; int rem = n % HW;   // rem = h*48 + w
    for (int i = 0; i < 4; ++i) {
      for (int r = 0; r < 4; ++r) {
        int m = i * 16 + quad * 4 + r;
        float v = acc[i][j][r];
        if (m < 18) {
          cls_ws[(long)(b * 18 + m) * HW + rem] = v + b_cls[m];
        } else if (m < 54) {
          out_bbox[(long)(b * 36 + (m - 18)) * HW + rem] = v + b_bbox[m - 18];
        }
      }
    }
  }
}

// ---------------- softmax over fg/bg pairs + NLL loss partials ---------------------------
// one thread per (b, a, h, w): 221184 = 864*256
__global__ void softmax_loss(const float* __restrict__ cls, const int* __restrict__ label,
                             float* __restrict__ prob, float* __restrict__ acc) {
  int idx = blockIdx.x * 256 + threadIdx.x;
  int b = idx / 27648; int r = idx % 27648;
  int a = r / HW; int r2 = r % HW;
  long i0 = (long)(b * 18 + a) * HW + r2;
  long i1 = i0 + (long)9 * HW;
  float x0 = cls[i0], x1 = cls[i1];
  float mx = fmaxf(x0, x1);
  float e0 = __expf(x0 - mx), e1 = __expf(x1 - mx);
  float s = e0 + e1;
  prob[i0] = e0 / s;
  prob[i1] = e1 / s;
  int lb = label[idx];
  float nll = 0.f, val = 0.f;
  if (lb != -1) {
    val = 1.f;
    float xl = (lb > 0) ? x1 : x0;
    nll = -(xl - mx - __logf(s));
  }
  nll = wave_sum(nll);
  val = wave_sum(val);
  __shared__ float red[8];
  int lane = threadIdx.x & 63, wv = threadIdx.x >> 6;
  if (lane == 0) { red[wv] = nll; red[4 + wv] = val; }
  __syncthreads();
  if (threadIdx.x == 0) {
    atomicAdd(&acc[0], red[0] + red[1] + red[2] + red[3]);
    atomicAdd(&acc[1], red[4] + red[5] + red[6] + red[7]);
  }
}

// ---------------- smooth-L1 box loss ------------------------------------------------------
__global__ void box_loss(const float* __restrict__ pred, const float* __restrict__ tgt,
                         const float* __restrict__ iw, const float* __restrict__ ow,
                         float* __restrict__ acc) {
  float s = 0.f;
  const long total = (long)B_ * 36 * HW;   // 884736
  for (long i = (long)blockIdx.x * 256 + threadIdx.x; i < total; i += (long)gridDim.x * 256) {
    float d = iw[i] * (pred[i] - tgt[i]);
    float ad = fabsf(d);
    float l = (ad < (1.f / 9.f)) ? d * d * 4.5f : ad - (1.f / 18.f);
    s += ow[i] * l;
  }
  s = wave_sum(s);
  __shared__ float red[4];
  int lane = threadIdx.x & 63, wv = threadIdx.x >> 6;
  if (lane == 0) red[wv] = s;
  __syncthreads();
  if (threadIdx.x == 0) atomicAdd(&acc[2], red[0] + red[1] + red[2] + red[3]);
}

__global__ void finalize(const float* __restrict__ acc, float* __restrict__ out) {
  if (threadIdx.x == 0) {
    out[0] = acc[0] / fmaxf(acc[1], 1.f);
    out[1] = acc[2] / (float)B_;
  }
}

extern "C" void kernel_launch(void* const* d_in, const int* in_sizes, int n_in,
                              void* d_out, int out_size, void* d_ws, size_t ws_size,
                              hipStream_t stream) {
  const float* base_feat = (const float*)d_in[0];
  const float* W_conv    = (const float*)d_in[1];
  const float* b_conv    = (const float*)d_in[2];
  const float* W_cls     = (const float*)d_in[3];
  const float* b_cls     = (const float*)d_in[4];
  const float* W_bbox    = (const float*)d_in[5];
  const float* b_bbox    = (const float*)d_in[6];
  const int*   rpn_label = (const int*)d_in[7];
  const float* bb_tgt    = (const float*)d_in[8];
  const float* bb_iw     = (const float*)d_in[9];
  const float* bb_ow     = (const float*)d_in[10];

  float* out = (float*)d_out;
  float* out_cls_prob = out;                         // 442368
  float* out_bbox     = out + 442368;                // 884736
  float* out_scalars  = out + 442368 + 884736;       // 2

  // workspace layout
  size_t off = 0;
  auto alloc = [&](size_t bytes) {
    void* p = (char*)d_ws + off;
    off = (off + bytes + 255) & ~(size_t)255;
    return p;
  };
  const size_t XT_BYTES = (size_t)B_ * HP * WP * CIN * 2;          // 54,067,200
  unsigned short* xt    = (unsigned short*)alloc(XT_BYTES);
  unsigned short* Wa    = (unsigned short*)alloc((size_t)OC * K9 * 2);
  unsigned short* conv1 = (unsigned short*)alloc((size_t)NPOS * OC * 2);
  unsigned short* Wh    = (unsigned short*)alloc((size_t)64 * 512 * 2);
  float* cls_ws         = (float*)alloc((size_t)B_ * 18 * HW * 4);
  float* accbuf         = (float*)alloc(16);

  hipMemsetAsync(xt, 0, XT_BYTES, stream);
  hipMemsetAsync(accbuf, 0, 16, stream);

  prep_x<<<dim3(8, 64, 8), 256, 0, stream>>>(base_feat, xt);
  prep_w<<<18432, 256, 0, stream>>>(W_conv, Wa);
  prep_wh<<<128, 256, 0, stream>>>(W_cls, W_bbox, Wh);
  conv_gemm<<<dim3(192, 4), 256, 0, stream>>>(Wa, xt, b_conv, conv1);
  head_gemm<<<192, 256, 0, stream>>>(Wh, conv1, b_cls, b_bbox, cls_ws, out_bbox);
  softmax_loss<<<864, 256, 0, stream>>>(cls_ws, rpn_label, out_cls_prob, accbuf);
  box_loss<<<1728, 256, 0, stream>>>(out_bbox, bb_tgt, bb_iw, bb_ow, accbuf);
  finalize<<<1, 64, 0, stream>>>(accbuf, out_scalars);
}

// Round 2
// 374.174 us; speedup vs baseline: 1.3859x; 1.3859x over previous
//
#include <hip/hip_runtime.h>
#include <stdint.h>

// Problem constants
#define B_    8
#define CIN   1024
#define H_    64
#define W_    48
#define OC    512
#define HW    3072          // H*W
#define NPOS  24576         // B*H*W
#define K9    9216          // 9*CIN
#define HP    66            // H+2
#define WP    50            // W+2

typedef __attribute__((ext_vector_type(8))) __bf16 bf16x8;
typedef __attribute__((ext_vector_type(4))) float  float4_t;
typedef __attribute__((ext_vector_type(4))) unsigned short ushort4_t;
typedef __attribute__((ext_vector_type(8))) int int8v;
typedef __attribute__((ext_vector_type(4))) int int4v;

__device__ __forceinline__ unsigned short f2bf(float x) {
  union { float f; unsigned u; } v; v.f = x;
  unsigned r = v.u + 0x7FFFu + ((v.u >> 16) & 1u);
  return (unsigned short)(r >> 16);
}

// pack 4 floats -> 4 fp8 e4m3 bytes (RNE, saturating)
__device__ __forceinline__ unsigned int pack4_fp8(float a, float b, float c, float d) {
  int w = __builtin_amdgcn_cvt_pk_fp8_f32(a, b, 0, false);   // bytes 0,1
  w = __builtin_amdgcn_cvt_pk_fp8_f32(c, d, w, true);        // bytes 2,3
  return (unsigned int)w;
}

__device__ __forceinline__ void async16(const void* g, void* l) {
  __builtin_amdgcn_global_load_lds(
      (const __attribute__((address_space(1))) unsigned int*)g,
      (__attribute__((address_space(3))) unsigned int*)l, 16, 0, 0);
}

__device__ __forceinline__ float wave_sum(float v) {
  for (int o = 32; o > 0; o >>= 1) v += __shfl_down(v, o, 64);
  return v;
}

// ---------------- prep: pad+transpose base_feat NCHW fp32 -> NHWC fp8 (x16 scale) --------
// grid (8 c-chunks, 64 h, 8 b), 256 threads
__global__ void prep_x(const float* __restrict__ x, unsigned char* __restrict__ xt) {
  int cx = blockIdx.x, h = blockIdx.y, b = blockIdx.z;
  __shared__ float tile[128 * 49];
  int t = threadIdx.x;
  const float* src = x + ((long)(b * CIN + cx * 128) * H_ + h) * W_;
  for (int it = 0; it < 24; ++it) {
    int e = it * 256 + t;
    int cl = e / 48, w = e % 48;
    tile[cl * 49 + w] = src[(long)cl * HW + w];
  }
  __syncthreads();
  unsigned char* dst = xt + ((long)(b * HP + h + 1) * WP + 1) * CIN + cx * 128;
  for (int it = 0; it < 6; ++it) {
    int e = it * 256 + t;
    int w = e >> 5, g = e & 31;
    float v0 = tile[(g * 4 + 0) * 49 + w] * 16.f;
    float v1 = tile[(g * 4 + 1) * 49 + w] * 16.f;
    float v2 = tile[(g * 4 + 2) * 49 + w] * 16.f;
    float v3 = tile[(g * 4 + 3) * 49 + w] * 16.f;
    *(unsigned int*)&dst[(long)w * CIN + g * 4] = pack4_fp8(v0, v1, v2, v3);
  }
}

// ---------------- prep: W_conv [512,1024,3,3] fp32 -> Wa [512, 9216] fp8 (x512 scale) ----
// one block per output channel o; coalesced row load into LDS, reordered fp8 write
__global__ void prep_w(const float* __restrict__ Wc, unsigned char* __restrict__ Wa) {
  __shared__ float lw[9216];
  int o = blockIdx.x, t = threadIdx.x;
  const float* src = Wc + (long)o * K9;
  for (int i = 0; i < 36; ++i) lw[i * 256 + t] = src[i * 256 + t];
  __syncthreads();
  unsigned char* dst = Wa + (long)o * K9;
  int c = t * 4;
  for (int off = 0; off < 9; ++off) {
    float v0 = lw[(c + 0) * 9 + off] * 512.f;
    float v1 = lw[(c + 1) * 9 + off] * 512.f;
    float v2 = lw[(c + 2) * 9 + off] * 512.f;
    float v3 = lw[(c + 3) * 9 + off] * 512.f;
    *(unsigned int*)&dst[off * 1024 + c] = pack4_fp8(v0, v1, v2, v3);
  }
}

// ---------------- prep: head weights -> Wh [64,512] bf16 (rows 54..63 zero) -------------
__global__ void prep_wh(const float* __restrict__ Wcls, const float* __restrict__ Wbb,
                        unsigned short* __restrict__ Wh) {
  int i = blockIdx.x * 256 + threadIdx.x;   // < 32768
  int m = i >> 9, c = i & 511;
  float v = 0.f;
  if (m < 18) v = Wcls[m * 512 + c];
  else if (m < 54) v = Wbb[(m - 18) * 512 + c];
  Wh[i] = f2bf(v);
}

// ---------------- main conv GEMM (MX-fp8): M=512, N=24576, K=9216 ------------------------
// 128x128 tile, K-step 128 (fp8). grid (192, 4), 256 threads.
// LDS tiles xor-swizzled at 16B-chunk granularity: phys_chunk = r*8 + (q ^ (r&7))
#define BKF 128
__global__ __launch_bounds__(256, 2)
void conv_gemm(const unsigned char* __restrict__ Wa, const unsigned char* __restrict__ xt,
               const float* __restrict__ bias, unsigned short* __restrict__ conv1) {
  __shared__ unsigned char As[128 * BKF];   // 16 KB
  __shared__ unsigned char Bs[128 * BKF];   // 16 KB
  int t = threadIdx.x;
  int lane = t & 63, wv = t >> 6;
  int m0 = blockIdx.y * 128;
  int n0 = blockIdx.x * 128;
  // staging: physical chunk c = s*256 + t  (s=0..3) -> row r=c>>3, swizzled q=(c&7)^(r&7)
  const unsigned char* aSrc[4];
  const unsigned char* bSrc[4];
  for (int s = 0; s < 4; ++s) {
    int c = s * 256 + t;
    int r = c >> 3;
    int q = (c & 7) ^ (r & 7);
    aSrc[s] = Wa + (long)(m0 + r) * K9 + q * 16;
    int n = n0 + r; int b = n / HW; int rem = n % HW; int h = rem / W_; int w = rem % W_;
    bSrc[s] = xt + ((long)(b * HP + h) * WP + w) * CIN + q * 16;
  }
  float4_t acc[4][4] = {};
  int wm = wv >> 1, wn = wv & 1;
  int quad = lane >> 4, col = lane & 15;
  for (int kt = 0; kt < 72; ++kt) {
    int off = kt >> 3;                       // which of the 9 (dy,dx) taps
    int dy = off / 3, dx = off % 3;
    long boff = (long)(dy * WP + dx) * CIN + (kt & 7) * 128;
    long aoff = (long)kt * 128;
    __syncthreads();
    for (int s = 0; s < 4; ++s)
      async16(aSrc[s] + aoff, &As[s * 4096 + wv * 1024]);
    for (int s = 0; s < 4; ++s)
      async16(bSrc[s] + boff, &Bs[s * 4096 + wv * 1024]);
    __syncthreads();
    int8v af[4], bfr[4];
    for (int i = 0; i < 4; ++i) {
      int r = wm * 64 + i * 16 + col;
      int rb = r * 128, x7 = r & 7;
      int4v lo = *(const int4v*)&As[rb + (((quad * 2 + 0) ^ x7) << 4)];
      int4v hi = *(const int4v*)&As[rb + (((quad * 2 + 1) ^ x7) << 4)];
      af[i] = (int8v){lo.x, lo.y, lo.z, lo.w, hi.x, hi.y, hi.z, hi.w};
    }
    for (int j = 0; j < 4; ++j) {
      int r = wn * 64 + j * 16 + col;
      int rb = r * 128, x7 = r & 7;
      int4v lo = *(const int4v*)&Bs[rb + (((quad * 2 + 0) ^ x7) << 4)];
      int4v hi = *(const int4v*)&Bs[rb + (((quad * 2 + 1) ^ x7) << 4)];
      bfr[j] = (int8v){lo.x, lo.y, lo.z, lo.w, hi.x, hi.y, hi.z, hi.w};
    }
    for (int i = 0; i < 4; ++i)
      for (int j = 0; j < 4; ++j)
        // A=W scaled by 2^9 -> e8m0 118 (2^-9); B=x scaled by 2^4 -> e8m0 123 (2^-4)
        acc[i][j] = __builtin_amdgcn_mfma_scale_f32_16x16x128_f8f6f4(
            af[i], bfr[j], acc[i][j], 0, 0, 0, 0x76767676, 0, 0x7B7B7B7B);
  }
  // epilogue: bias + relu, store bf16 conv1[n*512 + m], 8B packed along m
  for (int i = 0; i < 4; ++i) {
    int mb = m0 + wm * 64 + i * 16 + quad * 4;
    float b0 = bias[mb + 0], b1 = bias[mb + 1], b2 = bias[mb + 2], b3 = bias[mb + 3];
    for (int j = 0; j < 4; ++j) {
      int n = n0 + wn * 64 + j * 16 + col;
      ushort4_t pk;
      pk.x = f2bf(fmaxf(acc[i][j].x + b0, 0.f));
      pk.y = f2bf(fmaxf(acc[i][j].y + b1, 0.f));
      pk.z = f2bf(fmaxf(acc[i][j].z + b2, 0.f));
      pk.w = f2bf(fmaxf(acc[i][j].w + b3, 0.f));
      *(ushort4_t*)&conv1[(long)n * 512 + mb] = pk;
    }
  }
}

// ---------------- head GEMM: [64 x 512] @ conv1^T -> cls_score (ws) + bbox_pred (d_out) --
// M=64 (54 used), N=24576, K=512. Tile 64x128. grid 192, 256 threads.
__global__ __launch_bounds__(256, 2)
void head_gemm(const unsigned short* __restrict__ Wh, const unsigned short* __restrict__ conv1,
               const float* __restrict__ b_cls, const float* __restrict__ b_bbox,
               float* __restrict__ cls_ws, float* __restrict__ out_bbox) {
  __shared__ unsigned short As[64 * 32];
  __shared__ unsigned short Bs[128 * 32];
  int t = threadIdx.x;
  int lane = t & 63, wv = t >> 6;
  int n0 = blockIdx.x * 128;
  int srow = wv * 16 + (lane >> 2);
  int skof = (lane & 3) * 8;
  int quad = lane >> 4, col = lane & 15;
  float4_t acc[4][2] = {};
  for (int kt = 0; kt < 16; ++kt) {
    int k0 = kt * 32;
    __syncthreads();
    async16(Wh + (long)srow * 512 + k0 + skof, &As[wv * 512]);
    for (int q = 0; q < 2; ++q)
      async16(conv1 + (long)(n0 + q * 64 + srow) * 512 + k0 + skof, &Bs[q * 2048 + wv * 512]);
    __syncthreads();
    bf16x8 af[4], bfr[2];
    for (int i = 0; i < 4; ++i)
      af[i] = *(const bf16x8*)&As[(i * 16 + col) * 32 + quad * 8];
    for (int j = 0; j < 2; ++j)
      bfr[j] = *(const bf16x8*)&Bs[(wv * 32 + j * 16 + col) * 32 + quad * 8];
    for (int i = 0; i < 4; ++i)
      for (int j = 0; j < 2; ++j)
        acc[i][j] = __builtin_amdgcn_mfma_f32_16x16x32_bf16(af[i], bfr[j], acc[i][j], 0, 0, 0);
  }
  for (int j = 0; j < 2; ++j) {
    int n = n0 + wv * 32 + j * 16 + col;
    int b = n / HW; int rem = n % HW;   // rem = h*48 + w
    for (int i = 0; i < 4; ++i) {
      for (int r = 0; r < 4; ++r) {
        int m = i * 16 + quad * 4 + r;
        float v = acc[i][j][r];
        if (m < 18) {
          cls_ws[(long)(b * 18 + m) * HW + rem] = v + b_cls[m];
        } else if (m < 54) {
          out_bbox[(long)(b * 36 + (m - 18)) * HW + rem] = v + b_bbox[m - 18];
        }
      }
    }
  }
}

// ---------------- softmax over fg/bg pairs + NLL loss partials ---------------------------
// one thread per (b, a, h, w): 221184 = 864*256
__global__ void softmax_loss(const float* __restrict__ cls, const int* __restrict__ label,
                             float* __restrict__ prob, float* __restrict__ acc) {
  int idx = blockIdx.x * 256 + threadIdx.x;
  int b = idx / 27648; int r = idx % 27648;
  int a = r / HW; int r2 = r % HW;
  long i0 = (long)(b * 18 + a) * HW + r2;
  long i1 = i0 + (long)9 * HW;
  float x0 = cls[i0], x1 = cls[i1];
  float mx = fmaxf(x0, x1);
  float e0 = __expf(x0 - mx), e1 = __expf(x1 - mx);
  float s = e0 + e1;
  prob[i0] = e0 / s;
  prob[i1] = e1 / s;
  int lb = label[idx];
  float nll = 0.f, val = 0.f;
  if (lb != -1) {
    val = 1.f;
    float xl = (lb > 0) ? x1 : x0;
    nll = -(xl - mx - __logf(s));
  }
  nll = wave_sum(nll);
  val = wave_sum(val);
  __shared__ float red[8];
  int lane = threadIdx.x & 63, wv = threadIdx.x >> 6;
  if (lane == 0) { red[wv] = nll; red[4 + wv] = val; }
  __syncthreads();
  if (threadIdx.x == 0) {
    atomicAdd(&acc[0], red[0] + red[1] + red[2] + red[3]);
    atomicAdd(&acc[1], red[4] + red[5] + red[6] + red[7]);
  }
}

// ---------------- smooth-L1 box loss ------------------------------------------------------
__global__ void box_loss(const float* __restrict__ pred, const float* __restrict__ tgt,
                         const float* __restrict__ iw, const float* __restrict__ ow,
                         float* __restrict__ acc) {
  float s = 0.f;
  const long total = (long)B_ * 36 * HW;   // 884736
  for (long i = (long)blockIdx.x * 256 + threadIdx.x; i < total; i += (long)gridDim.x * 256) {
    float d = iw[i] * (pred[i] - tgt[i]);
    float ad = fabsf(d);
    float l = (ad < (1.f / 9.f)) ? d * d * 4.5f : ad - (1.f / 18.f);
    s += ow[i] * l;
  }
  s = wave_sum(s);
  __shared__ float red[4];
  int lane = threadIdx.x & 63, wv = threadIdx.x >> 6;
  if (lane == 0) red[wv] = s;
  __syncthreads();
  if (threadIdx.x == 0) atomicAdd(&acc[2], red[0] + red[1] + red[2] + red[3]);
}

__global__ void finalize(const float* __restrict__ acc, float* __restrict__ out) {
  if (threadIdx.x == 0) {
    out[0] = acc[0] / fmaxf(acc[1], 1.f);
    out[1] = acc[2] / (float)B_;
  }
}

extern "C" void kernel_launch(void* const* d_in, const int* in_sizes, int n_in,
                              void* d_out, int out_size, void* d_ws, size_t ws_size,
                              hipStream_t stream) {
  const float* base_feat = (const float*)d_in[0];
  const float* W_conv    = (const float*)d_in[1];
  const float* b_conv    = (const float*)d_in[2];
  const float* W_cls     = (const float*)d_in[3];
  const float* b_cls     = (const float*)d_in[4];
  const float* W_bbox    = (const float*)d_in[5];
  const float* b_bbox    = (const float*)d_in[6];
  const int*   rpn_label = (const int*)d_in[7];
  const float* bb_tgt    = (const float*)d_in[8];
  const float* bb_iw     = (const float*)d_in[9];
  const float* bb_ow     = (const float*)d_in[10];

  float* out = (float*)d_out;
  float* out_cls_prob = out;                         // 442368
  float* out_bbox     = out + 442368;                // 884736
  float* out_scalars  = out + 442368 + 884736;       // 2

  // workspace layout
  size_t off = 0;
  auto alloc = [&](size_t bytes) {
    void* p = (char*)d_ws + off;
    off = (off + bytes + 255) & ~(size_t)255;
    return p;
  };
  const size_t XT_BYTES = (size_t)B_ * HP * WP * CIN;              // 27,033,600 (fp8)
  unsigned char*  xt    = (unsigned char*)alloc(XT_BYTES);
  unsigned char*  Wa    = (unsigned char*)alloc((size_t)OC * K9);
  unsigned short* conv1 = (unsigned short*)alloc((size_t)NPOS * OC * 2);
  unsigned short* Wh    = (unsigned short*)alloc((size_t)64 * 512 * 2);
  float* cls_ws         = (float*)alloc((size_t)B_ * 18 * HW * 4);
  float* accbuf         = (float*)alloc(16);

  hipMemsetAsync(xt, 0, XT_BYTES, stream);
  hipMemsetAsync(accbuf, 0, 16, stream);

  prep_x<<<dim3(8, 64, 8), 256, 0, stream>>>(base_feat, xt);
  prep_w<<<512, 256, 0, stream>>>(W_conv, Wa);
  prep_wh<<<128, 256, 0, stream>>>(W_cls, W_bbox, Wh);
  conv_gemm<<<dim3(192, 4), 256, 0, stream>>>(Wa, xt, b_conv, conv1);
  head_gemm<<<192, 256, 0, stream>>>(Wh, conv1, b_cls, b_bbox, cls_ws, out_bbox);
  softmax_loss<<<864, 256, 0, stream>>>(cls_ws, rpn_label, out_cls_prob, accbuf);
  box_loss<<<1728, 256, 0, stream>>>(out_bbox, bb_tgt, bb_iw, bb_ow, accbuf);
  finalize<<<1, 64, 0, stream>>>(accbuf, out_scalars);
}

// Round 3
// 355.177 us; speedup vs baseline: 1.4600x; 1.0535x over previous
//
#include <hip/hip_runtime.h>
#include <stdint.h>

// Problem constants
#define B_    8
#define CIN   1024
#define H_    64
#define W_    48
#define OC    512
#define HW    3072          // H*W
#define NPOS  24576         // B*H*W
#define K9    9216          // 9*CIN
#define HP    66            // H+2
#define WP    50            // W+2

typedef __attribute__((ext_vector_type(8))) __bf16 bf16x8;
typedef __attribute__((ext_vector_type(4))) float  float4_t;
typedef __attribute__((ext_vector_type(4))) unsigned short ushort4_t;
typedef __attribute__((ext_vector_type(8))) int int8v;
typedef __attribute__((ext_vector_type(4))) int int4v;

__device__ __forceinline__ unsigned short f2bf(float x) {
  union { float f; unsigned u; } v; v.f = x;
  unsigned r = v.u + 0x7FFFu + ((v.u >> 16) & 1u);
  return (unsigned short)(r >> 16);
}

// pack 4 floats -> 4 fp8 e4m3 bytes (RNE, saturating)
__device__ __forceinline__ unsigned int pack4_fp8(float a, float b, float c, float d) {
  int w = __builtin_amdgcn_cvt_pk_fp8_f32(a, b, 0, false);   // bytes 0,1
  w = __builtin_amdgcn_cvt_pk_fp8_f32(c, d, w, true);        // bytes 2,3
  return (unsigned int)w;
}

__device__ __forceinline__ void async16(const void* g, void* l) {
  __builtin_amdgcn_global_load_lds(
      (const __attribute__((address_space(1))) unsigned int*)g,
      (__attribute__((address_space(3))) unsigned int*)l, 16, 0, 0);
}

__device__ __forceinline__ float wave_sum(float v) {
  for (int o = 32; o > 0; o >>= 1) v += __shfl_down(v, o, 64);
  return v;
}

// ================= fused prep: prep_x | prep_w | prep_wh | borders ======================
// grid = 4096 (prep_x) + 512 (prep_w) + 32 (prep_wh) + 528 (borders) = 5168, 256 threads
__global__ void prep_fused(const float* __restrict__ x, const float* __restrict__ Wc,
                           const float* __restrict__ Wcls, const float* __restrict__ Wbb,
                           unsigned char* __restrict__ xt, unsigned char* __restrict__ Wa,
                           unsigned short* __restrict__ Wh, float* __restrict__ accbuf) {
  __shared__ float smem[9216];   // 36 KB shared across branches
  int bid = blockIdx.x, t = threadIdx.x;
  if (bid < 4096) {
    // ---- prep_x: pad+transpose NCHW fp32 -> NHWC fp8 (x16), one (b,h,128c) slice ----
    int cx = bid & 7, h = (bid >> 3) & 63, b = bid >> 9;
    float* tile = smem;   // [128][49]
    const float* src = x + ((long)(b * CIN + cx * 128) * H_ + h) * W_;
    for (int it = 0; it < 6; ++it) {
      int e = it * 256 + t;
      int cl = e / 12, w4 = e % 12;
      float4_t v = *(const float4_t*)&src[(long)cl * HW + w4 * 4];
      int base = cl * 49 + w4 * 4;
      tile[base] = v.x; tile[base + 1] = v.y; tile[base + 2] = v.z; tile[base + 3] = v.w;
    }
    __syncthreads();
    unsigned char* dst = xt + ((long)(b * HP + h + 1) * WP + 1) * CIN + cx * 128;
    for (int it = 0; it < 6; ++it) {
      int e = it * 256 + t;
      int w = e >> 5, g = e & 31;
      float v0 = tile[(g * 4 + 0) * 49 + w] * 16.f;
      float v1 = tile[(g * 4 + 1) * 49 + w] * 16.f;
      float v2 = tile[(g * 4 + 2) * 49 + w] * 16.f;
      float v3 = tile[(g * 4 + 3) * 49 + w] * 16.f;
      *(unsigned int*)&dst[(long)w * CIN + g * 4] = pack4_fp8(v0, v1, v2, v3);
    }
  } else if (bid < 4608) {
    // ---- prep_w: W_conv [512,1024,3,3] -> Wa [512,9216] fp8 (x512), k=(off*1024+c) ----
    int o = bid - 4096;
    float* lw = smem;   // [9216]
    const float* src = Wc + (long)o * K9;
    for (int i = 0; i < 9; ++i)
      *(float4_t*)&lw[i * 1024 + t * 4] = *(const float4_t*)&src[i * 1024 + t * 4];
    __syncthreads();
    unsigned char* dst = Wa + (long)o * K9;
    int c = t * 4;
    for (int off = 0; off < 9; ++off) {
      float v0 = lw[(c + 0) * 9 + off] * 512.f;
      float v1 = lw[(c + 1) * 9 + off] * 512.f;
      float v2 = lw[(c + 2) * 9 + off] * 512.f;
      float v3 = lw[(c + 3) * 9 + off] * 512.f;
      *(unsigned int*)&dst[off * 1024 + c] = pack4_fp8(v0, v1, v2, v3);
    }
  } else if (bid < 4640) {
    // ---- prep_wh: head weights -> Wh [64,512] bf16 (rows 54..63 zero) ----
    int e = (bid - 4608) * 1024 + t * 4;
    int m = e >> 9, c = e & 511;
    float v0 = 0.f, v1 = 0.f, v2 = 0.f, v3 = 0.f;
    if (m < 18) {
      const float* s = Wcls + m * 512 + c;
      v0 = s[0]; v1 = s[1]; v2 = s[2]; v3 = s[3];
    } else if (m < 54) {
      const float* s = Wbb + (m - 18) * 512 + c;
      v0 = s[0]; v1 = s[1]; v2 = s[2]; v3 = s[3];
    }
    ushort4_t pk; pk.x = f2bf(v0); pk.y = f2bf(v1); pk.z = f2bf(v2); pk.w = f2bf(v3);
    *(ushort4_t*)&Wh[e] = pk;
    if (bid == 4608 && t < 4) accbuf[t] = 0.f;
  } else {
    // ---- borders: zero-pad halo of xt ----
    int bid2 = bid - 4640;
    int b = bid2 / 66, h = bid2 % 66;
    unsigned char* base = xt + (long)(b * 66 + h) * 50 * 1024;
    int4v z = {};
    if (h == 0 || h == 65) {
      for (int i = t; i < 3200; i += 256) *(int4v*)(base + (long)i * 16) = z;
    } else if (t < 128) {
      int which = t >> 6, off = t & 63;
      *(int4v*)(base + (long)which * 49 * 1024 + (long)off * 16) = z;
    }
  }
}

// ---------------- main conv GEMM (MX-fp8): M=512, N=24576, K=9216 ------------------------
// 128x128 tile, K-step 128 (fp8). grid (192, 4), 256 threads.
// LDS tiles xor-swizzled at 16B-chunk granularity: phys_chunk = r*8 + (q ^ (r&7))
#define BKF 128
__global__ __launch_bounds__(256, 2)
void conv_gemm(const unsigned char* __restrict__ Wa, const unsigned char* __restrict__ xt,
               const float* __restrict__ bias, unsigned short* __restrict__ conv1) {
  __shared__ unsigned char As[128 * BKF];   // 16 KB
  __shared__ unsigned char Bs[128 * BKF];   // 16 KB
  int t = threadIdx.x;
  int lane = t & 63, wv = t >> 6;
  int m0 = blockIdx.y * 128;
  int n0 = blockIdx.x * 128;
  const unsigned char* aSrc[4];
  const unsigned char* bSrc[4];
  for (int s = 0; s < 4; ++s) {
    int c = s * 256 + t;
    int r = c >> 3;
    int q = (c & 7) ^ (r & 7);
    aSrc[s] = Wa + (long)(m0 + r) * K9 + q * 16;
    int n = n0 + r; int b = n / HW; int rem = n % HW; int h = rem / W_; int w = rem % W_;
    bSrc[s] = xt + ((long)(b * HP + h) * WP + w) * CIN + q * 16;
  }
  float4_t acc[4][4] = {};
  int wm = wv >> 1, wn = wv & 1;
  int quad = lane >> 4, col = lane & 15;
  for (int kt = 0; kt < 72; ++kt) {
    int off = kt >> 3;                       // which of the 9 (dy,dx) taps
    int dy = off / 3, dx = off % 3;
    long boff = (long)(dy * WP + dx) * CIN + (kt & 7) * 128;
    long aoff = (long)kt * 128;
    __syncthreads();
    for (int s = 0; s < 4; ++s)
      async16(aSrc[s] + aoff, &As[s * 4096 + wv * 1024]);
    for (int s = 0; s < 4; ++s)
      async16(bSrc[s] + boff, &Bs[s * 4096 + wv * 1024]);
    __syncthreads();
    int8v af[4], bfr[4];
    for (int i = 0; i < 4; ++i) {
      int r = wm * 64 + i * 16 + col;
      int rb = r * 128, x7 = r & 7;
      int4v lo = *(const int4v*)&As[rb + (((quad * 2 + 0) ^ x7) << 4)];
      int4v hi = *(const int4v*)&As[rb + (((quad * 2 + 1) ^ x7) << 4)];
      af[i] = (int8v){lo.x, lo.y, lo.z, lo.w, hi.x, hi.y, hi.z, hi.w};
    }
    for (int j = 0; j < 4; ++j) {
      int r = wn * 64 + j * 16 + col;
      int rb = r * 128, x7 = r & 7;
      int4v lo = *(const int4v*)&Bs[rb + (((quad * 2 + 0) ^ x7) << 4)];
      int4v hi = *(const int4v*)&Bs[rb + (((quad * 2 + 1) ^ x7) << 4)];
      bfr[j] = (int8v){lo.x, lo.y, lo.z, lo.w, hi.x, hi.y, hi.z, hi.w};
    }
    for (int i = 0; i < 4; ++i)
      for (int j = 0; j < 4; ++j)
        // A=W scaled by 2^9 -> e8m0 118 (2^-9); B=x scaled by 2^4 -> e8m0 123 (2^-4)
        acc[i][j] = __builtin_amdgcn_mfma_scale_f32_16x16x128_f8f6f4(
            af[i], bfr[j], acc[i][j], 0, 0, 0, 0x76767676, 0, 0x7B7B7B7B);
  }
  // epilogue: bias + relu, store bf16 conv1[n*512 + m], 8B packed along m
  for (int i = 0; i < 4; ++i) {
    int mb = m0 + wm * 64 + i * 16 + quad * 4;
    float b0 = bias[mb + 0], b1 = bias[mb + 1], b2 = bias[mb + 2], b3 = bias[mb + 3];
    for (int j = 0; j < 4; ++j) {
      int n = n0 + wn * 64 + j * 16 + col;
      ushort4_t pk;
      pk.x = f2bf(fmaxf(acc[i][j].x + b0, 0.f));
      pk.y = f2bf(fmaxf(acc[i][j].y + b1, 0.f));
      pk.z = f2bf(fmaxf(acc[i][j].z + b2, 0.f));
      pk.w = f2bf(fmaxf(acc[i][j].w + b3, 0.f));
      *(ushort4_t*)&conv1[(long)n * 512 + mb] = pk;
    }
  }
}

// ---------------- head GEMM: [64 x 512] @ conv1^T -> cls_score (ws) + bbox_pred (d_out) --
// M=64 (54 used), N=24576, K=512. Tile 64(N) x BK=128. grid 384, 256 threads.
// 16B-chunk xor swizzle (16 chunks/row): phys = q ^ (r&15)
__global__ __launch_bounds__(256, 2)
void head_gemm(const unsigned short* __restrict__ Wh, const unsigned short* __restrict__ conv1,
               const float* __restrict__ b_cls, const float* __restrict__ b_bbox,
               float* __restrict__ cls_ws, float* __restrict__ out_bbox) {
  __shared__ unsigned short As[64 * 128];   // 16 KB
  __shared__ unsigned short Bs[64 * 128];   // 16 KB
  int t = threadIdx.x;
  int lane = t & 63, wv = t >> 6;
  int n0 = blockIdx.x * 64;
  int quad = lane >> 4, col = lane & 15;
  const unsigned short* aS[4];
  const unsigned short* bS[4];
  for (int p = 0; p < 4; ++p) {
    int c = p * 256 + t;
    int r = c >> 4;
    int q = (c & 15) ^ (r & 15);
    aS[p] = Wh + (long)r * 512 + q * 8;
    bS[p] = conv1 + (long)(n0 + r) * 512 + q * 8;
  }
  float4_t acc[4] = {};
  for (int kt = 0; kt < 4; ++kt) {
    long koff = (long)kt * 128;
    __syncthreads();
    for (int p = 0; p < 4; ++p) async16(aS[p] + koff, &As[p * 2048 + wv * 512]);
    for (int p = 0; p < 4; ++p) async16(bS[p] + koff, &Bs[p * 2048 + wv * 512]);
    __syncthreads();
    for (int ks = 0; ks < 4; ++ks) {
      int rn = wv * 16 + col;
      bf16x8 bfr = *(const bf16x8*)&Bs[rn * 128 + (((ks * 4 + quad) ^ (rn & 15)) << 3)];
      for (int i = 0; i < 4; ++i) {
        int r = i * 16 + col;
        bf16x8 af = *(const bf16x8*)&As[r * 128 + (((ks * 4 + quad) ^ (r & 15)) << 3)];
        acc[i] = __builtin_amdgcn_mfma_f32_16x16x32_bf16(af, bfr, acc[i], 0, 0, 0);
      }
    }
  }
  int n = n0 + wv * 16 + col;
  int b = n / HW; int rem = n % HW;   // rem = h*48 + w
  for (int i = 0; i < 4; ++i) {
    for (int r = 0; r < 4; ++r) {
      int m = i * 16 + quad * 4 + r;
      float v = acc[i][r];
      if (m < 18) {
        cls_ws[(long)(b * 18 + m) * HW + rem] = v + b_cls[m];
      } else if (m < 54) {
        out_bbox[(long)(b * 36 + (m - 18)) * HW + rem] = v + b_bbox[m - 18];
      }
    }
  }
}

// ---------------- fused losses: softmax+NLL (blocks 0..863) | smooth-L1 box (864..2591) --
__global__ void loss_fused(const float* __restrict__ cls, const int* __restrict__ label,
                           float* __restrict__ prob,
                           const float* __restrict__ pred, const float* __restrict__ tgt,
                           const float* __restrict__ iw, const float* __restrict__ ow,
                           float* __restrict__ acc) {
  int lane = threadIdx.x & 63, wv = threadIdx.x >> 6;
  __shared__ float red[8];
  if (blockIdx.x < 864) {
    int idx = blockIdx.x * 256 + threadIdx.x;
    int b = idx / 27648; int r = idx % 27648;
    int a = r / HW; int r2 = r % HW;
    long i0 = (long)(b * 18 + a) * HW + r2;
    long i1 = i0 + (long)9 * HW;
    float x0 = cls[i0], x1 = cls[i1];
    float mx = fmaxf(x0, x1);
    float e0 = __expf(x0 - mx), e1 = __expf(x1 - mx);
    float s = e0 + e1;
    prob[i0] = e0 / s;
    prob[i1] = e1 / s;
    int lb = label[idx];
    float nll = 0.f, val = 0.f;
    if (lb != -1) {
      val = 1.f;
      float xl = (lb > 0) ? x1 : x0;
      nll = -(xl - mx - __logf(s));
    }
    nll = wave_sum(nll);
    val = wave_sum(val);
    if (lane == 0) { red[wv] = nll; red[4 + wv] = val; }
    __syncthreads();
    if (threadIdx.x == 0) {
      atomicAdd(&acc[0], red[0] + red[1] + red[2] + red[3]);
      atomicAdd(&acc[1], red[4] + red[5] + red[6] + red[7]);
    }
  } else {
    int bid = blockIdx.x - 864;
    float s = 0.f;
    const long total = (long)B_ * 36 * HW;   // 884736
    for (long i = (long)bid * 256 + threadIdx.x; i < total; i += (long)1728 * 256) {
      float d = iw[i] * (pred[i] - tgt[i]);
      float ad = fabsf(d);
      float l = (ad < (1.f / 9.f)) ? d * d * 4.5f : ad - (1.f / 18.f);
      s += ow[i] * l;
    }
    s = wave_sum(s);
    if (lane == 0) red[wv] = s;
    __syncthreads();
    if (threadIdx.x == 0) atomicAdd(&acc[2], red[0] + red[1] + red[2] + red[3]);
  }
}

__global__ void finalize(const float* __restrict__ acc, float* __restrict__ out) {
  if (threadIdx.x == 0) {
    out[0] = acc[0] / fmaxf(acc[1], 1.f);
    out[1] = acc[2] / (float)B_;
  }
}

extern "C" void kernel_launch(void* const* d_in, const int* in_sizes, int n_in,
                              void* d_out, int out_size, void* d_ws, size_t ws_size,
                              hipStream_t stream) {
  const float* base_feat = (const float*)d_in[0];
  const float* W_conv    = (const float*)d_in[1];
  const float* b_conv    = (const float*)d_in[2];
  const float* W_cls     = (const float*)d_in[3];
  const float* b_cls     = (const float*)d_in[4];
  const float* W_bbox    = (const float*)d_in[5];
  const float* b_bbox    = (const float*)d_in[6];
  const int*   rpn_label = (const int*)d_in[7];
  const float* bb_tgt    = (const float*)d_in[8];
  const float* bb_iw     = (const float*)d_in[9];
  const float* bb_ow     = (const float*)d_in[10];

  float* out = (float*)d_out;
  float* out_cls_prob = out;                         // 442368
  float* out_bbox     = out + 442368;                // 884736
  float* out_scalars  = out + 442368 + 884736;       // 2

  // workspace layout
  size_t off = 0;
  auto alloc = [&](size_t bytes) {
    void* p = (char*)d_ws + off;
    off = (off + bytes + 255) & ~(size_t)255;
    return p;
  };
  const size_t XT_BYTES = (size_t)B_ * HP * WP * CIN;              // 27,033,600 (fp8)
  unsigned char*  xt    = (unsigned char*)alloc(XT_BYTES);
  unsigned char*  Wa    = (unsigned char*)alloc((size_t)OC * K9);
  unsigned short* conv1 = (unsigned short*)alloc((size_t)NPOS * OC * 2);
  unsigned short* Wh    = (unsigned short*)alloc((size_t)64 * 512 * 2);
  float* cls_ws         = (float*)alloc((size_t)B_ * 18 * HW * 4);
  float* accbuf         = (float*)alloc(16);

  prep_fused<<<5168, 256, 0, stream>>>(base_feat, W_conv, W_cls, W_bbox, xt, Wa, Wh, accbuf);
  conv_gemm<<<dim3(192, 4), 256, 0, stream>>>(Wa, xt, b_conv, conv1);
  head_gemm<<<384, 256, 0, stream>>>(Wh, conv1, b_cls, b_bbox, cls_ws, out_bbox);
  loss_fused<<<2592, 256, 0, stream>>>(cls_ws, rpn_label, out_cls_prob,
                                       out_bbox, bb_tgt, bb_iw, bb_ow, accbuf);
  finalize<<<1, 64, 0, stream>>>(accbuf, out_scalars);
}